// Round 11
// baseline (58.826 us; speedup 1.0000x reference)
//
#include <hip/hip_runtime.h>

using u32 = unsigned int;

typedef __attribute__((ext_vector_type(8))) _Float16 f16x8;
typedef __attribute__((ext_vector_type(4))) float    f32x4;

// ---------------------------------------------------------------------------
// prep: WcatT[n][kk] = s(i,kb) * W[c][(i^kb)*256 + u]   (f16, 1024x1024)
// sign bits packed: bit (4*i + kb) of 0x3950
// ---------------------------------------------------------------------------
__global__ __launch_bounds__(256) void build_wcatT(const float* __restrict__ W,
                                                   _Float16* __restrict__ Wt) {
    int t  = blockIdx.x * 256 + threadIdx.x;
    int n  = t >> 10, kk = t & 1023;
    int kb = n >> 8,  u  = n & 255;
    int i  = kk >> 8, c  = kk & 255;
    int j  = i ^ kb;
    float v = W[c * 1024 + j * 256 + u];
    if ((0x3950u >> (i * 4 + kb)) & 1u) v = -v;
    Wt[t] = (_Float16)v;
}

// ---------------------------------------------------------------------------
// GEMM, fused f32->f16 A-cast.  M=16384 N=1024 K=1024.
//   BM=128 BN=256 BK=32, 3-buffer LDS (3 x 24KB = 72KB) -> 2 blocks/CU.
//   8 waves (2M x 4N, 64x64 each, acc[4][4]).  Grid 512.
//   ONE barrier + 16 MFMA per tile; counted VMW(4); distance-2 staging.
//   A: reg-staged (2 GL16 -> 8 cvt -> 1 swizzled ds_write_b128).
//   B: gload_lds, pre-swizzled source (proven 0-conflict path).
// ---------------------------------------------------------------------------
__device__ __forceinline__ void async16(const void* g, void* l) {
    __builtin_amdgcn_global_load_lds((const __attribute__((address_space(1))) u32*)g,
                                     (__attribute__((address_space(3))) u32*)l,
                                     16, 0, 0);
}

#define BARRIER() do { asm volatile("" ::: "memory"); \
                       __builtin_amdgcn_s_barrier(); \
                       asm volatile("" ::: "memory"); } while (0)

#define VMW(n)  asm volatile("s_waitcnt vmcnt(" #n ")" ::: "memory")
#define LGKM0() asm volatile("s_waitcnt lgkmcnt(0)" ::: "memory")
#define SB0()   __builtin_amdgcn_sched_barrier(0)

#define GL16(dst, ptr, off) \
    asm volatile("global_load_dwordx4 %0, %1, off offset:" #off \
                 : "=v"(dst) : "v"(ptr))

#define MFMA(av, bv, c) __builtin_amdgcn_mfma_f32_16x16x32_f16(av, bv, c, 0, 0, 0)

#define MM16() do { \
    __builtin_amdgcn_s_setprio(1); \
    acc[0][0]=MFMA(a0,b0,acc[0][0]); acc[0][1]=MFMA(a0,b1,acc[0][1]); \
    acc[0][2]=MFMA(a0,b2,acc[0][2]); acc[0][3]=MFMA(a0,b3,acc[0][3]); \
    acc[1][0]=MFMA(a1,b0,acc[1][0]); acc[1][1]=MFMA(a1,b1,acc[1][1]); \
    acc[1][2]=MFMA(a1,b2,acc[1][2]); acc[1][3]=MFMA(a1,b3,acc[1][3]); \
    acc[2][0]=MFMA(a2,b0,acc[2][0]); acc[2][1]=MFMA(a2,b1,acc[2][1]); \
    acc[2][2]=MFMA(a2,b2,acc[2][2]); acc[2][3]=MFMA(a2,b3,acc[2][3]); \
    acc[3][0]=MFMA(a3,b0,acc[3][0]); acc[3][1]=MFMA(a3,b1,acc[3][1]); \
    acc[3][2]=MFMA(a3,b2,acc[3][2]); acc[3][3]=MFMA(a3,b3,acc[3][3]); \
    __builtin_amdgcn_s_setprio(0); \
    __builtin_amdgcn_sched_barrier(0); \
} while (0)

// A K-tile U: row ar (0..127), 32B f32 chunk ac -> 2 GL16 (8 f32/thread)
#define ISSUE_A(U, d0, d1) do { \
    const float* _p = pA + (size_t)((U) >> 3) * 4194304 + ((U) & 7) * 32; \
    GL16(d0, _p, 0); GL16(d1, _p, 16); \
} while (0)

// B K-tile U -> buf SB (2 x gload_lds/thread; source pre-swizzled, dest linear)
#define STAGE_B(U, SB) do { \
    const int _g = (U) * 32; \
    _Float16* _d = lds + (SB) * 12288 + 4096 + tid * 8; \
    async16(gB0 + _g, _d); \
    async16(gB0 + 131072 + _g, _d + 4096); \
} while (0)

// cvt 8 f32 -> 1 swizzled ds_write_b128 into buf SB's A region
#define WRITE_A(SB, s0, s1) do { \
    f16x8 h; \
    h[0]=(_Float16)(s0)[0]; h[1]=(_Float16)(s0)[1]; \
    h[2]=(_Float16)(s0)[2]; h[3]=(_Float16)(s0)[3]; \
    h[4]=(_Float16)(s1)[0]; h[5]=(_Float16)(s1)[1]; \
    h[6]=(_Float16)(s1)[2]; h[7]=(_Float16)(s1)[3]; \
    *(f16x8*)(lds + (SB) * 12288 + aw0) = h; \
} while (0)

// tile T: reads buf BUF; issues A(T+3)/B(T+2); 16 MFMA; gate; write A(T+2)
#define TILE(T, BUF, SBUF, DO_ISSUE, I0, I1, DO_STAGE, DO_WRITE, W0, W1, GATE, GATE2) do { \
    const _Float16* Ab = lds + (BUF) * 12288; \
    f16x8 a0, a1, a2, a3, b0, b1, b2, b3; \
    a0 = *(const f16x8*)(Ab + aoff);        a1 = *(const f16x8*)(Ab + aoff + 512); \
    a2 = *(const f16x8*)(Ab + aoff + 1024); a3 = *(const f16x8*)(Ab + aoff + 1536); \
    b0 = *(const f16x8*)(Ab + boff);        b1 = *(const f16x8*)(Ab + boff + 512); \
    b2 = *(const f16x8*)(Ab + boff + 1024); b3 = *(const f16x8*)(Ab + boff + 1536); \
    if (DO_ISSUE) { ISSUE_A((T) + 3, I0, I1); } \
    if (DO_STAGE) { STAGE_B((T) + 2, SBUF); } \
    MM16(); \
    GATE; SB0(); \
    if (DO_WRITE) { WRITE_A(SBUF, W0, W1); } \
    GATE2; \
    LGKM0(); \
    BARRIER(); \
} while (0)

__global__ __launch_bounds__(512, 2) void ga_gemm(const float* __restrict__ A,    // x f32
                                                  const _Float16* __restrict__ Bt,// WcatT
                                                  const float*  __restrict__ bias,
                                                  float* __restrict__ out) {
    __shared__ _Float16 lds[3 * 12288] __attribute__((aligned(16)));  // 72 KiB

    const int tid  = threadIdx.x;
    const int lane = tid & 63;
    const int wid  = tid >> 6;
    const int wm   = wid >> 2;          // 0..1  (M half of 128)
    const int wn   = wid & 3;           // 0..3  (N quarter of 256)
    const int l15  = lane & 15;
    const int lg   = lane >> 4;

    // XCD swizzle: 512 blocks, 64/XCD; 4 consecutive = same A m-panel
    const int bid = blockIdx.x;
    const int swz = (bid & 7) * 64 + (bid >> 3);
    const int mt  = swz >> 2, nt = swz & 3;     // 128 m-tiles x 4 n-tiles
    const int m0  = mt * 128,  n0 = nt * 256;

    // A staging: 4 threads/row; row ar (0..127), 32B chunk ac (0..3)
    const int ar = tid >> 2, ac = tid & 3;
    const float* pA = A + (size_t)(m0 + ar) * 256 + ac * 8;
    const int aw0 = ar * 32 + (ac ^ ((ar >> 1) & 3)) * 8;   // f16 units

    // B staging (slot s -> row s>>2, chunk s&3; source chunk pre-swizzled)
    const int r0 = tid >> 2;
    const int g0 = (tid & 3) ^ ((r0 >> 1) & 3);
    const _Float16* gB0 = Bt + (size_t)(n0 + r0) * 1024 + g0 * 8;
    // rows +128 at gB0 + 131072 (same swizzle phase)

    // fragment ds_read offsets (f16 units); B region at +4096
    const int sc   = lg ^ ((l15 >> 1) & 3);
    const int aoff = (wm * 64 + l15) * 32 + sc * 8;
    const int boff = 4096 + (wn * 64 + l15) * 32 + sc * 8;

    f32x4 acc[4][4] = {};
    f32x4 u0, u1, v0, v1;

    // prologue: A0->u, A1->v, B0->buf0, B1->buf1; write A0,A1; A2->u
    ISSUE_A(0, u0, u1);
    ISSUE_A(1, v0, v1);
    STAGE_B(0, 0);
    STAGE_B(1, 1);
    VMW(6);  SB0();                 // A0 landed
    WRITE_A(0, u0, u1);
    VMW(4);  SB0();                 // A1 landed
    WRITE_A(1, v0, v1);
    LGKM0();                        // u,v free
    ISSUE_A(2, u0, u1);             // queue: [B0, B1, A2]
    VMW(4);                         // B0 landed; enter loop with [B1, A2]
    LGKM0();
    BARRIER();

    // steady tiles 0..23 (even: issue->v, write<-u; odd: issue->u, write<-v)
    for (int t = 0; t < 24; t += 6) {
        TILE(t + 0, 0, 2, 1, v0, v1, 1, 1, u0, u1, VMW(4), (void)0);
        TILE(t + 1, 1, 0, 1, u0, u1, 1, 1, v0, v1, VMW(4), (void)0);
        TILE(t + 2, 2, 1, 1, v0, v1, 1, 1, u0, u1, VMW(4), (void)0);
        TILE(t + 3, 0, 2, 1, u0, u1, 1, 1, v0, v1, VMW(4), (void)0);
        TILE(t + 4, 1, 0, 1, v0, v1, 1, 1, u0, u1, VMW(4), (void)0);
        TILE(t + 5, 2, 1, 1, u0, u1, 1, 1, v0, v1, VMW(4), (void)0);
    }
    // steady tiles 24..28
    TILE(24, 0, 2, 1, v0, v1, 1, 1, u0, u1, VMW(4), (void)0);
    TILE(25, 1, 0, 1, u0, u1, 1, 1, v0, v1, VMW(4), (void)0);
    TILE(26, 2, 1, 1, v0, v1, 1, 1, u0, u1, VMW(4), (void)0);
    TILE(27, 0, 2, 1, u0, u1, 1, 1, v0, v1, VMW(4), (void)0);
    TILE(28, 1, 0, 1, v0, v1, 1, 1, u0, u1, VMW(4), (void)0);  // A31->v, write A30
    // tail: tile 29 (stage B31, write A31<-v, drain B30), 30 (drain B31), 31
    TILE(29, 2, 1, 0, u0, u1, 1, 1, v0, v1, VMW(4), VMW(2));
    TILE(30, 0, 0, 0, u0, u1, 0, 0, u0, u1, VMW(0), (void)0);
    TILE(31, 1, 0, 0, u0, u1, 0, 0, u0, u1, (void)0, (void)0);

    // epilogue: C/D layout col=lane&15 (n), row=(lane>>4)*4+rr (m)
    const size_t outBase = (size_t)nt * 16384 * 256;   // blade kb == nt
    const int ucol = wn * 64 + l15;
    float bv[4];
#pragma unroll
    for (int fn = 0; fn < 4; ++fn) bv[fn] = bias[nt * 256 + ucol + fn * 16];
#pragma unroll
    for (int fm = 0; fm < 4; ++fm) {
        const int m = m0 + wm * 64 + fm * 16 + lg * 4;
#pragma unroll
        for (int rr = 0; rr < 4; ++rr) {
            float* op = out + outBase + (size_t)(m + rr) * 256;
#pragma unroll
            for (int fn = 0; fn < 4; ++fn)
                op[ucol + fn * 16] = acc[fm][fn][rr] + bv[fn];
        }
    }
}

// ---------------------------------------------------------------------------
extern "C" void kernel_launch(void* const* d_in, const int* in_sizes, int n_in,
                              void* d_out, int out_size, void* d_ws, size_t ws_size,
                              hipStream_t stream) {
    (void)in_sizes; (void)n_in; (void)out_size; (void)ws_size;
    const float* x = (const float*)d_in[0];   // (65536, 256)
    const float* W = (const float*)d_in[1];   // (256, 1024)
    const float* b = (const float*)d_in[2];   // (1024,)
    float* out = (float*)d_out;               // (65536, 256)

    _Float16* Wt = (_Float16*)d_ws;           // 2 MB

    build_wcatT<<<4096, 256, 0, stream>>>(W, Wt);
    ga_gemm<<<512, 512, 0, stream>>>(x, Wt, b, out);
}

// Round 12
// 52.845 us; speedup vs baseline: 1.1132x; 1.1132x over previous
//
#include <hip/hip_runtime.h>

using u32 = unsigned int;

typedef __attribute__((ext_vector_type(8))) _Float16 f16x8;
typedef __attribute__((ext_vector_type(4))) float    f32x4;

// ---------------------------------------------------------------------------
// prep: WcatT[n][kk] = s(i,kb) * W[c][(i^kb)*256 + u]   (f16, 1024x1024)
// sign bits packed: bit (4*i + kb) of 0x3950
// ---------------------------------------------------------------------------
__global__ __launch_bounds__(256) void build_wcatT(const float* __restrict__ W,
                                                   _Float16* __restrict__ Wt) {
    int t  = blockIdx.x * 256 + threadIdx.x;
    int n  = t >> 10, kk = t & 1023;
    int kb = n >> 8,  u  = n & 255;
    int i  = kk >> 8, c  = kk & 255;
    int j  = i ^ kb;
    float v = W[c * 1024 + j * 256 + u];
    if ((0x3950u >> (i * 4 + kb)) & 1u) v = -v;
    Wt[t] = (_Float16)v;
}

// ---------------------------------------------------------------------------
// GEMM with fused f32->f16 A-cast (R10 skeleton, ONE barrier per tile):
//   M=16384 N=1024 K=1024. 256x256 tile, BK=32, 4 LDS buffers (128KB),
//   8 waves (2M x 4N). 32 MFMA between barriers. 6 vmem/tile, VMW(6) ledger.
//   A: reg-staged 4-threads/row; B: gload_lds pre-swizzled (0 conflicts).
// ---------------------------------------------------------------------------
__device__ __forceinline__ void async16(const void* g, void* l) {
    __builtin_amdgcn_global_load_lds((const __attribute__((address_space(1))) u32*)g,
                                     (__attribute__((address_space(3))) u32*)l,
                                     16, 0, 0);
}

#define BARRIER() do { asm volatile("" ::: "memory"); \
                       __builtin_amdgcn_s_barrier(); \
                       asm volatile("" ::: "memory"); } while (0)

#define VMW(n)  asm volatile("s_waitcnt vmcnt(" #n ")" ::: "memory")
#define LGKM0() asm volatile("s_waitcnt lgkmcnt(0)" ::: "memory")
#define SB0()   __builtin_amdgcn_sched_barrier(0)

#define GL16(dst, ptr, off) \
    asm volatile("global_load_dwordx4 %0, %1, off offset:" #off \
                 : "=v"(dst) : "v"(ptr))

#define MFMA(av, bv, c) __builtin_amdgcn_mfma_f32_16x16x32_f16(av, bv, c, 0, 0, 0)

#define PHASE_MFMA(f0, f1, f2, f3) do { \
    __builtin_amdgcn_s_setprio(1); \
    acc[f0][0]=MFMA(a0,b0,acc[f0][0]); acc[f0][1]=MFMA(a0,b1,acc[f0][1]); \
    acc[f0][2]=MFMA(a0,b2,acc[f0][2]); acc[f0][3]=MFMA(a0,b3,acc[f0][3]); \
    acc[f1][0]=MFMA(a1,b0,acc[f1][0]); acc[f1][1]=MFMA(a1,b1,acc[f1][1]); \
    acc[f1][2]=MFMA(a1,b2,acc[f1][2]); acc[f1][3]=MFMA(a1,b3,acc[f1][3]); \
    acc[f2][0]=MFMA(a2,b0,acc[f2][0]); acc[f2][1]=MFMA(a2,b1,acc[f2][1]); \
    acc[f2][2]=MFMA(a2,b2,acc[f2][2]); acc[f2][3]=MFMA(a2,b3,acc[f2][3]); \
    acc[f3][0]=MFMA(a3,b0,acc[f3][0]); acc[f3][1]=MFMA(a3,b1,acc[f3][1]); \
    acc[f3][2]=MFMA(a3,b2,acc[f3][2]); acc[f3][3]=MFMA(a3,b3,acc[f3][3]); \
    __builtin_amdgcn_s_setprio(0); \
    __builtin_amdgcn_sched_barrier(0); \
} while (0)

// B K-tile U -> buf BI (2 x gload_lds/thread, source pre-swizzled)
#define STAGE_B(U, BI) do { \
    const int _b = (BI) * 16384 + 8192; \
    const int _g = (U) * 32; \
    async16(gB0 + _g, lds + _b + tid * 8); \
    async16(gB1 + _g, lds + _b + 4096 + tid * 8); \
} while (0)

// A K-tile U: 2 slots (rows ar, ar+128), contiguous 32B f32 per slot (4 GL16)
#define ISSUE_A(U, d0, d1, d2, d3) do { \
    const float* _p = pA + (size_t)((U) >> 3) * 4194304 + ((U) & 7) * 32; \
    GL16(d0, _p, 0); GL16(d1, _p, 16); \
    const float* _q = _p + 32768; \
    GL16(d2, _q, 0); GL16(d3, _q, 16); \
} while (0)

// cvt 16 f32 -> 2 swizzled ds_write_b128 (slot0 -> aw0, slot1 -> aw0+4096)
#define WRITE_A(BI, s0, s1, s2, s3) do { \
    f16x8 h0, h1; \
    h0[0]=(_Float16)(s0)[0]; h0[1]=(_Float16)(s0)[1]; h0[2]=(_Float16)(s0)[2]; h0[3]=(_Float16)(s0)[3]; \
    h0[4]=(_Float16)(s1)[0]; h0[5]=(_Float16)(s1)[1]; h0[6]=(_Float16)(s1)[2]; h0[7]=(_Float16)(s1)[3]; \
    h1[0]=(_Float16)(s2)[0]; h1[1]=(_Float16)(s2)[1]; h1[2]=(_Float16)(s2)[2]; h1[3]=(_Float16)(s2)[3]; \
    h1[4]=(_Float16)(s3)[0]; h1[5]=(_Float16)(s3)[1]; h1[6]=(_Float16)(s3)[2]; h1[7]=(_Float16)(s3)[3]; \
    _Float16* _wp = lds + (BI) * 16384 + aw0; \
    *(f16x8*)(_wp) = h0; \
    *(f16x8*)(_wp + 4096) = h1; \
} while (0)

// tile T (single barrier): issue A(T+3)+B(T+2); reads; MM1; reads2;
//   GATE; WRITE_A(T+2); MM2; LGKM0; BARRIER
#define TILE(T, DO_ISSUE, I0,I1,I2,I3, DO_STAGE, DO_WRITE, W0,W1,W2,W3, GATE) do { \
    const _Float16* Ab = lds + ((T) & 3) * 16384; \
    const _Float16* Bb = Ab + 8192; \
    f16x8 a0, a1, a2, a3, b0, b1, b2, b3; \
    if (DO_ISSUE) { ISSUE_A((T) + 3, I0, I1, I2, I3); } \
    if (DO_STAGE) { STAGE_B((T) + 2, ((T) + 2) & 3); } \
    a0 = *(const f16x8*)(Ab + aoff);        a1 = *(const f16x8*)(Ab + aoff + 512); \
    a2 = *(const f16x8*)(Ab + aoff + 1024); a3 = *(const f16x8*)(Ab + aoff + 1536); \
    b0 = *(const f16x8*)(Bb + boff);        b1 = *(const f16x8*)(Bb + boff + 512); \
    b2 = *(const f16x8*)(Bb + boff + 1024); b3 = *(const f16x8*)(Bb + boff + 1536); \
    PHASE_MFMA(0, 1, 2, 3); \
    a0 = *(const f16x8*)(Ab + aoff + 2048); a1 = *(const f16x8*)(Ab + aoff + 2560); \
    a2 = *(const f16x8*)(Ab + aoff + 3072); a3 = *(const f16x8*)(Ab + aoff + 3584); \
    GATE; \
    SB0(); \
    if (DO_WRITE) { WRITE_A((((T) + 2) & 3), W0, W1, W2, W3); } \
    PHASE_MFMA(4, 5, 6, 7); \
    LGKM0(); \
    BARRIER(); \
} while (0)

__global__ __launch_bounds__(512, 2) void ga_gemm(const float* __restrict__ A,    // x f32
                                                  const _Float16* __restrict__ Bt,// WcatT
                                                  const float*  __restrict__ bias,
                                                  float* __restrict__ out) {
    __shared__ _Float16 lds[4 * 16384] __attribute__((aligned(16)));  // 128 KiB

    const int tid  = threadIdx.x;
    const int lane = tid & 63;
    const int wid  = tid >> 6;
    const int wm   = wid >> 2;          // 0..1
    const int wn   = wid & 3;           // 0..3
    const int l15  = lane & 15;
    const int lg   = lane >> 4;

    // XCD-aware bijective swizzle: 256 blocks, 8 XCDs, 32 contiguous each
    const int bid = blockIdx.x;
    const int swz = (bid & 7) * 32 + (bid >> 3);
    const int mt  = swz >> 2, nt = swz & 3;
    const int m0  = mt * 256,  n0 = nt * 256;

    // A staging: 4 threads/row; slots (ar, ac) and (ar+128, ac), 32B each
    const int ar = tid >> 2, ac = tid & 3;
    const float* pA = A + (size_t)(m0 + ar) * 256 + ac * 8;
    const int aw0 = ar * 32 + (ac ^ ((ar >> 1) & 3)) * 8;   // f16 units

    // B staging (slot s -> row s>>2, chunk s&3; source pre-swizzled)
    const int s1 = 512 + tid;
    const int r0 = tid >> 2,  r1 = s1 >> 2;
    const int g0 = (tid & 3) ^ ((r0 >> 1) & 3);
    const int g1 = (s1 & 3)  ^ ((r1 >> 1) & 3);
    const _Float16* gB0 = Bt + (size_t)(n0 + r0) * 1024 + g0 * 8;
    const _Float16* gB1 = Bt + (size_t)(n0 + r1) * 1024 + g1 * 8;

    // ds_read fragment offsets (f16 units), swizzled chunk per thread
    const int sc   = lg ^ ((l15 >> 1) & 3);
    const int aoff = (wm * 128 + l15) * 32 + sc * 8;
    const int boff = (wn * 64  + l15) * 32 + sc * 8;

    f32x4 acc[8][4] = {};
    f32x4 u0, u1, u2, u3, v0, v1, v2, v3;

    // prologue: A(0)->u, A(1)->v, B(0), B(1); write A(0),A(1); issue A(2)->u
    ISSUE_A(0, u0, u1, u2, u3);
    ISSUE_A(1, v0, v1, v2, v3);
    STAGE_B(0, 0);
    STAGE_B(1, 1);
    VMW(8);  SB0();                  // A(0) landed
    WRITE_A(0, u0, u1, u2, u3);
    VMW(4);  SB0();                  // A(1) landed
    WRITE_A(1, v0, v1, v2, v3);
    LGKM0();                         // ds_writes sourcing u,v consumed
    ISSUE_A(2, u0, u1, u2, u3);      // queue: [B0:2, B1:2, A2:4]
    VMW(6);                          // B(0) landed; enter with [B1:2, A2:4]
    LGKM0();
    BARRIER();

    // steady: T even -> issue v / write u; T odd -> issue u / write v
    for (int t = 0; t < 28; t += 2) {
        TILE(t,     1, v0,v1,v2,v3, 1, 1, u0,u1,u2,u3, VMW(6));
        TILE(t + 1, 1, u0,u1,u2,u3, 1, 1, v0,v1,v2,v3, VMW(6));
    }
    TILE(28, 1, v0,v1,v2,v3, 1, 1, u0,u1,u2,u3, VMW(6));   // A(31)->v, write A(30)
    TILE(29, 0, u0,u1,u2,u3, 1, 1, v0,v1,v2,v3, VMW(2));   // stage B(31), write A(31)
    TILE(30, 0, u0,u1,u2,u3, 0, 0, u0,u1,u2,u3, VMW(0));   // drain B(31)
    TILE(31, 0, u0,u1,u2,u3, 0, 0, u0,u1,u2,u3, (void)0);

    // epilogue: C/D layout col=lane&15, row=(lane>>4)*4+r
    const size_t outBase = (size_t)nt * 16384 * 256;
    const int ucol = wn * 64 + l15;
    float bv[4];
#pragma unroll
    for (int fn = 0; fn < 4; ++fn) bv[fn] = bias[nt * 256 + ucol + fn * 16];
#pragma unroll
    for (int fm = 0; fm < 8; ++fm) {
        const int m = m0 + wm * 128 + fm * 16 + lg * 4;
#pragma unroll
        for (int r = 0; r < 4; ++r) {
            float* op = out + outBase + (size_t)(m + r) * 256;
#pragma unroll
            for (int fn = 0; fn < 4; ++fn)
                op[ucol + fn * 16] = acc[fm][fn][r] + bv[fn];
        }
    }
}

// ---------------------------------------------------------------------------
extern "C" void kernel_launch(void* const* d_in, const int* in_sizes, int n_in,
                              void* d_out, int out_size, void* d_ws, size_t ws_size,
                              hipStream_t stream) {
    (void)in_sizes; (void)n_in; (void)out_size; (void)ws_size;
    const float* x = (const float*)d_in[0];   // (65536, 256)
    const float* W = (const float*)d_in[1];   // (256, 1024)
    const float* b = (const float*)d_in[2];   // (1024,)
    float* out = (float*)d_out;               // (65536, 256)

    _Float16* Wt = (_Float16*)d_ws;           // 2 MB

    build_wcatT<<<4096, 256, 0, stream>>>(W, Wt);
    ga_gemm<<<256, 512, 0, stream>>>(x, Wt, b, out);
}